// Round 4
// baseline (884.046 us; speedup 1.0000x reference)
//
#include <hip/hip_runtime.h>
#include <stdint.h>

// ---------------------------------------------------------------------------
// ManifoldAugmentation: x (8192,256) fp32 ->
//   out = concat([x, (1-alpha)*x + alpha*x[sel]]) (16384,256) fp32
// sel = nbrs[i][choice], nbrs = 5 nearest neighbors (excluding self).
// PRNG: JAX threefry, PARTITIONABLE semantics (jax_threefry_partitionable=True,
// default in modern JAX): split/random_bits use 64-bit linear-index counters,
// 32-bit draws are out0^out1.
// ---------------------------------------------------------------------------

#define NROWS 8192
#define ND4   64          // 256 dims = 64 float4

// ------------------------- threefry2x32 (20 rounds) ------------------------
__device__ __forceinline__ uint32_t rotl32(uint32_t v, int d) {
  return (v << d) | (v >> (32 - d));
}

__device__ __forceinline__ void tf2x32(uint32_t k0, uint32_t k1,
                                       uint32_t& x0, uint32_t& x1) {
  const uint32_t ks2 = k0 ^ k1 ^ 0x1BD11BDAu;
  x0 += k0; x1 += k1;
#define TFR(R) { x0 += x1; x1 = rotl32(x1, R); x1 ^= x0; }
  TFR(13) TFR(15) TFR(26) TFR(6)
  x0 += k1;  x1 += ks2 + 1u;
  TFR(17) TFR(29) TFR(16) TFR(24)
  x0 += ks2; x1 += k0 + 2u;
  TFR(13) TFR(15) TFR(26) TFR(6)
  x0 += k0;  x1 += k1 + 3u;
  TFR(17) TFR(29) TFR(16) TFR(24)
  x0 += k1;  x1 += ks2 + 4u;
  TFR(13) TFR(15) TFR(26) TFR(6)
  x0 += ks2; x1 += k0 + 5u;
#undef TFR
}

// --------------------- top-6 (val,idx) lexicographic -----------------------
__device__ __forceinline__ bool lessp(float a, int ai, float b, int bi) {
  return (a < b) || ((a == b) && (ai < bi));
}

__device__ __forceinline__ void insert6(float key, int idx,
                                        float (&v)[6], int (&ix)[6]) {
  if (!lessp(key, idx, v[5], ix[5])) return;
#pragma unroll
  for (int j = 5; j >= 1; --j) {
    if (lessp(key, idx, v[j - 1], ix[j - 1])) {
      v[j] = v[j - 1]; ix[j] = ix[j - 1];
    } else {
      v[j] = key; ix[j] = idx; return;
    }
  }
  v[0] = key; ix[0] = idx;
}

// ------------------------------ kernel 1: sq -------------------------------
__global__ void sq_kernel(const float* __restrict__ x, float* __restrict__ sq) {
  int row  = blockIdx.x * 4 + (threadIdx.x >> 6);
  int lane = threadIdx.x & 63;
  const float4* xv4 = reinterpret_cast<const float4*>(x);
  float4 vv = xv4[row * ND4 + lane];
  float t = vv.x * vv.x + vv.y * vv.y + vv.z * vv.z + vv.w * vv.w;
#pragma unroll
  for (int off = 32; off >= 1; off >>= 1) t += __shfl_down(t, off);
  if (lane == 0) sq[row] = t;
}

// ------------------------------ kernel 2: knn ------------------------------
// grid 512 = 128 row-tiles (64 rows) x 4 col-quarters (2048 cols)
// block 512 threads = 8 waves; wave w sweeps cols [q*2048 + w*256, +256)
// lane = row; per-lane top-6 in registers; A (64 rows x 256 dims) in LDS.
__global__ __launch_bounds__(512, 4)
void knn_kernel(const float* __restrict__ x, const float* __restrict__ sq,
                float* __restrict__ candV, int* __restrict__ candI) {
  __shared__ __align__(16) char smem[65536];
  float4* As4 = reinterpret_cast<float4*>(smem);
  const float4* xv4 = reinterpret_cast<const float4*>(x);

  const int tid = threadIdx.x;
  const int bid = blockIdx.x;
  const int rowBase = (bid >> 2) * 64;
  const int q = bid & 3;

  // stage A: 64 rows x 64 float4, XOR-swizzled for conflict-free lane reads
#pragma unroll
  for (int it = 0; it < 8; ++it) {
    int flat = it * 512 + tid;          // 0..4095
    int r = flat >> 6, d4 = flat & 63;
    As4[r * 64 + (d4 ^ (r & 15))] = xv4[(rowBase + r) * ND4 + d4];
  }
  __syncthreads();

  const int w    = __builtin_amdgcn_readfirstlane(tid >> 6);
  const int lane = tid & 63;
  const int colBase = q * 2048 + w * 256;
  const int abase = lane * 64;
  const int s     = lane & 15;
  const float sqi = sq[rowBase + lane];

  float v[6]; int ix[6];
#pragma unroll
  for (int t = 0; t < 6; ++t) { v[t] = 3.402823466e38f; ix[t] = 0x7fffffff; }

  for (int cg = 0; cg < 32; ++cg) {
    const int c0 = colBase + cg * 8;
    float acc[8];
#pragma unroll
    for (int c = 0; c < 8; ++c) acc[c] = 0.0f;
    const float4* bp = xv4 + (size_t)c0 * ND4;
#pragma unroll 2
    for (int d4 = 0; d4 < 64; ++d4) {
      float4 a = As4[abase + (d4 ^ s)];
#pragma unroll
      for (int c = 0; c < 8; ++c) {
        float4 b = bp[c * ND4 + d4];    // wave-uniform address -> s_load
        acc[c] = fmaf(a.x, b.x, acc[c]);
        acc[c] = fmaf(a.y, b.y, acc[c]);
        acc[c] = fmaf(a.z, b.z, acc[c]);
        acc[c] = fmaf(a.w, b.w, acc[c]);
      }
    }
#pragma unroll
    for (int c = 0; c < 8; ++c) {
      int j = c0 + c;
      float s2 = sqi + sq[j];           // mimic reference rounding:
      float t2 = 2.0f * acc[c];         // exact (power-of-two scale)
      float key = s2 - t2;              // = fl(sq_i+sq_j) - 2*dot, 1 rounding
      insert6(key, j, v, ix);
    }
  }

  __syncthreads();   // done with As; reuse LDS for the cross-wave merge
  float* mv = reinterpret_cast<float*>(smem);          // [8][64][6] floats
  int*   mi = reinterpret_cast<int*>(smem + 12288);    // [8][64][6] ints
#pragma unroll
  for (int t = 0; t < 6; ++t) {
    mv[(w * 64 + lane) * 6 + t] = v[t];
    mi[(w * 64 + lane) * 6 + t] = ix[t];
  }
  __syncthreads();
  if (tid < 64) {
    float fv[6]; int fx[6];
#pragma unroll
    for (int t = 0; t < 6; ++t) { fv[t] = 3.402823466e38f; fx[t] = 0x7fffffff; }
    for (int ww = 0; ww < 8; ++ww) {
#pragma unroll
      for (int t = 0; t < 6; ++t)
        insert6(mv[(ww * 64 + tid) * 6 + t], mi[(ww * 64 + tid) * 6 + t], fv, fx);
    }
    int row = rowBase + tid;
    size_t base = (size_t)(q * NROWS + row) * 6;
#pragma unroll
    for (int t = 0; t < 6; ++t) { candV[base + t] = fv[t]; candI[base + t] = fx[t]; }
  }
}

// ------------------------------ kernel 3: pick -----------------------------
// merge 4 quarter-lists per row; position 0 = self; neighbors = 1..5.
// PRNG (partitionable threefry):
//   rng = fold_in(key(42), 0)        = cipher(key=(0,42), ctr=(0,0))
//   kc  = cipher(rng, (0,0)), ka = cipher(rng, (0,1))          [split]
//   k1  = cipher(kc,  (0,0)), k2 = cipher(kc,  (0,1))          [randint split]
//   bits(key, i) = out0 ^ out1 of cipher(key, ctr=(0,i))       [random_bits]
//   choice = (hb%5 + lb%5) % 5   (multiplier = (2^16 % 5)^2 % 5 = 1)
//   alpha  = bitcast((ub>>9) | 0x3F800000) - 1, clamped >= 0
__global__ void pick_kernel(const float* __restrict__ candV,
                            const int* __restrict__ candI,
                            int* __restrict__ sel, float* __restrict__ alph) {
  int r = blockIdx.x * 256 + threadIdx.x;
  float v[6]; int ix[6];
#pragma unroll
  for (int t = 0; t < 6; ++t) { v[t] = 3.402823466e38f; ix[t] = 0x7fffffff; }
  for (int qq = 0; qq < 4; ++qq) {
    size_t base = (size_t)(qq * NROWS + r) * 6;
#pragma unroll
    for (int t = 0; t < 6; ++t) insert6(candV[base + t], candI[base + t], v, ix);
  }

  uint32_t rg0 = 0, rg1 = 0; tf2x32(0u, 42u, rg0, rg1);     // fold_in(key(42),0)
  uint32_t kc0 = 0, kc1 = 0; tf2x32(rg0, rg1, kc0, kc1);    // split -> kc
  uint32_t ka0 = 0, ka1 = 1; tf2x32(rg0, rg1, ka0, ka1);    // split -> ka
  uint32_t k10 = 0, k11 = 0; tf2x32(kc0, kc1, k10, k11);    // randint split -> k1
  uint32_t k20 = 0, k21 = 1; tf2x32(kc0, kc1, k20, k21);    // randint split -> k2

  uint32_t ri = (uint32_t)r;
  uint32_t h0 = 0, h1 = ri; tf2x32(k10, k11, h0, h1); uint32_t hb = h0 ^ h1;
  uint32_t l0 = 0, l1 = ri; tf2x32(k20, k21, l0, l1); uint32_t lb = l0 ^ l1;
  uint32_t u0 = 0, u1 = ri; tf2x32(ka0, ka1, u0, u1); uint32_t ub = u0 ^ u1;

  uint32_t ch = (hb % 5u + lb % 5u) % 5u;
  float al = __uint_as_float((ub >> 9) | 0x3F800000u) - 1.0f;
  al = fmaxf(0.0f, al);

  int sl = ix[1];
  sl = (ch == 1u) ? ix[2] : sl;
  sl = (ch == 2u) ? ix[3] : sl;
  sl = (ch == 3u) ? ix[4] : sl;
  sl = (ch == 4u) ? ix[5] : sl;
  sel[r]  = sl;
  alph[r] = al;
}

// ------------------------------ kernel 4: emit -----------------------------
__global__ void emit_kernel(const float* __restrict__ x,
                            const int* __restrict__ sel,
                            const float* __restrict__ alph,
                            float* __restrict__ out) {
  const float4* xv4 = reinterpret_cast<const float4*>(x);
  float4* out4 = reinterpret_cast<float4*>(out);
  int gid = blockIdx.x * 256 + threadIdx.x;
#pragma unroll
  for (int it = 0; it < 4; ++it) {
    int u = gid + it * 262144;          // 16384*64 = 1,048,576 float4 total
    int orow = u >> 6;
    if (orow < NROWS) {
      out4[u] = xv4[u];
    } else {
      int i  = orow - NROWS;
      float a = alph[i];
      int  si = sel[i];
      int  d4 = u & 63;
      float4 xi = xv4[i * ND4 + d4];
      float4 xs = xv4[si * ND4 + d4];
      float om = 1.0f - a;
      out4[u] = make_float4(om * xi.x + a * xs.x, om * xi.y + a * xs.y,
                            om * xi.z + a * xs.z, om * xi.w + a * xs.w);
    }
  }
}

// ------------------------------- launcher ----------------------------------
extern "C" void kernel_launch(void* const* d_in, const int* in_sizes, int n_in,
                              void* d_out, int out_size, void* d_ws, size_t ws_size,
                              hipStream_t stream) {
  const float* x = (const float*)d_in[0];
  float* out = (float*)d_out;
  float* ws  = (float*)d_ws;

  // ws layout (floats): sq[8192] | candV[4*8192*6] | candI[4*8192*6] |
  //                     sel[8192] | alpha[8192]   (~1.7 MB total)
  float* sq    = ws;
  float* candV = ws + NROWS;
  int*   candI = (int*)(ws + NROWS + 4 * NROWS * 6);
  int*   sel   = (int*)(ws + NROWS + 2 * 4 * NROWS * 6);
  float* alph  = ws + NROWS + 2 * 4 * NROWS * 6 + NROWS;

  hipLaunchKernelGGL(sq_kernel,   dim3(2048), dim3(256), 0, stream, x, sq);
  hipLaunchKernelGGL(knn_kernel,  dim3(512),  dim3(512), 0, stream, x, sq, candV, candI);
  hipLaunchKernelGGL(pick_kernel, dim3(32),   dim3(256), 0, stream, candV, candI, sel, alph);
  hipLaunchKernelGGL(emit_kernel, dim3(1024), dim3(256), 0, stream, x, sel, alph, out);
}

// Round 5
// 279.392 us; speedup vs baseline: 3.1642x; 3.1642x over previous
//
#include <hip/hip_runtime.h>
#include <stdint.h>

// ---------------------------------------------------------------------------
// ManifoldAugmentation: x (8192,256) fp32 ->
//   out = concat([x, (1-alpha)*x + alpha*x[sel]]) (16384,256) fp32
// Stage 1: bf16 MFMA GEMM candidate kNN (top-6 per 32-col slice -> 96/row)
// Stage 2: fp32 rescore of top-16 candidates, bit-exact round-4 score order
// PRNG: JAX threefry, partitionable semantics (verified PASS in round 4).
// ---------------------------------------------------------------------------

#define NROWS 8192
#define ND4   64

typedef __attribute__((ext_vector_type(8))) short bf16x8;
typedef __attribute__((ext_vector_type(4))) float f32x4;

// ------------------------- threefry2x32 (20 rounds) ------------------------
__device__ __forceinline__ uint32_t rotl32(uint32_t v, int d) {
  return (v << d) | (v >> (32 - d));
}

__device__ __forceinline__ void tf2x32(uint32_t k0, uint32_t k1,
                                       uint32_t& x0, uint32_t& x1) {
  const uint32_t ks2 = k0 ^ k1 ^ 0x1BD11BDAu;
  x0 += k0; x1 += k1;
#define TFR(R) { x0 += x1; x1 = rotl32(x1, R); x1 ^= x0; }
  TFR(13) TFR(15) TFR(26) TFR(6)
  x0 += k1;  x1 += ks2 + 1u;
  TFR(17) TFR(29) TFR(16) TFR(24)
  x0 += ks2; x1 += k0 + 2u;
  TFR(13) TFR(15) TFR(26) TFR(6)
  x0 += k0;  x1 += k1 + 3u;
  TFR(17) TFR(29) TFR(16) TFR(24)
  x0 += k1;  x1 += ks2 + 4u;
  TFR(13) TFR(15) TFR(26) TFR(6)
  x0 += ks2; x1 += k0 + 5u;
#undef TFR
}

// --------------------- top-6 (val,idx) lexicographic -----------------------
__device__ __forceinline__ bool lessp(float a, int ai, float b, int bi) {
  return (a < b) || ((a == b) && (ai < bi));
}

__device__ __forceinline__ void insert6(float key, int idx,
                                        float (&v)[6], int (&ix)[6]) {
  if (!lessp(key, idx, v[5], ix[5])) return;
#pragma unroll
  for (int j = 5; j >= 1; --j) {
    if (lessp(key, idx, v[j - 1], ix[j - 1])) {
      v[j] = v[j - 1]; ix[j] = ix[j - 1];
    } else {
      v[j] = key; ix[j] = idx; return;
    }
  }
  v[0] = key; ix[0] = idx;
}

// ----------------------------- small helpers -------------------------------
__device__ __forceinline__ unsigned short f2bf(float f) {
  uint32_t u = __float_as_uint(f);
  u += 0x7FFFu + ((u >> 16) & 1u);          // RNE
  return (unsigned short)(u >> 16);
}

__device__ __forceinline__ void gload_lds16(const void* g, void* l) {
  __builtin_amdgcn_global_load_lds(
      (const __attribute__((address_space(1))) unsigned int*)g,
      (__attribute__((address_space(3))) unsigned int*)l, 16, 0, 0);
}

// ------------------------------ kernel 1: prep -----------------------------
// sq[row] (identical reduce order to the round-4 sq_kernel) + bf16 convert.
__global__ void prep_kernel(const float* __restrict__ x,
                            float* __restrict__ sq,
                            unsigned short* __restrict__ xbf) {
  int row  = blockIdx.x * 4 + (threadIdx.x >> 6);
  int lane = threadIdx.x & 63;
  const float4* xv4 = reinterpret_cast<const float4*>(x);
  float4 vv = xv4[(size_t)row * ND4 + lane];
  float t = vv.x * vv.x + vv.y * vv.y + vv.z * vv.z + vv.w * vv.w;
#pragma unroll
  for (int off = 32; off >= 1; off >>= 1) t += __shfl_down(t, off);
  if (lane == 0) sq[row] = t;
  ushort4 st;
  st.x = f2bf(vv.x); st.y = f2bf(vv.y); st.z = f2bf(vv.z); st.w = f2bf(vv.w);
  *reinterpret_cast<ushort4*>(xbf + (size_t)row * 256 + lane * 4) = st;
}

// --------------------------- kernel 2: gemm+topk ---------------------------
// grid 256 = 32 row-blocks (256 rows) x 8 col-chunks (1024 cols); 512 thr.
// 8 waves, each owns a 32-row stripe; A-frags in regs; B-tile (64x256 bf16,
// 32KB) double-buffered in LDS (XOR-swizzled src, linear dest); per-tile
// scores -> LDS col-major [64][260]; scan threads (2/row) keep per-slice
// top-6 candidates over all 16 tiles.
__global__ __launch_bounds__(512, 2)
void gemm_topk_kernel(const unsigned short* __restrict__ xbf,
                      const float* __restrict__ sq,
                      uint32_t* __restrict__ cand) {
  __shared__ __align__(16) char smem[132096];   // 2x32KB B + 66560B scores
  float* scores = reinterpret_cast<float*>(smem + 65536);

  const int tid = threadIdx.x;
  const int bid = blockIdx.x;
  const int rowblk = bid & 31;
  const int chunk  = bid >> 5;
  const int rowbase = rowblk * 256;
  const int colbase = chunk * 1024;
  const int w  = tid >> 6;
  const int l  = tid & 63;
  const int g  = l >> 4;
  const int c  = l & 15;
  const int l7 = l & 7;

  // A fragments: rows rowbase + w*32 + m*16 + c, k-chunk (4kb+g)
  uint4 afr[16];
#pragma unroll
  for (int m = 0; m < 2; ++m)
#pragma unroll
    for (int kb = 0; kb < 8; ++kb)
      afr[m * 8 + kb] = *reinterpret_cast<const uint4*>(
          xbf + (size_t)(rowbase + w * 32 + m * 16 + c) * 256 + (4 * kb + g) * 8);

  float sqi[8];
#pragma unroll
  for (int m = 0; m < 2; ++m)
#pragma unroll
    for (int e = 0; e < 4; ++e)
      sqi[m * 4 + e] = sq[rowbase + w * 32 + m * 16 + g * 4 + e];

  float lv[6]; int lcx[6];
#pragma unroll
  for (int j = 0; j < 6; ++j) { lv[j] = 3.402823466e38f; lcx[j] = 0x7fffffff; }
  const int srow = tid >> 1, shalf = tid & 1;

  int buf = 0;
  // prologue: stage tile 0 into buf 0
#pragma unroll
  for (int i = 0; i < 4; ++i) {
    int p = i * 512 + tid;
    int br = p >> 5, kc = p & 31;
    gload_lds16(xbf + (size_t)(colbase + br) * 256 + ((kc ^ (br & 7)) * 8),
                smem + p * 16);
  }
  __syncthreads();

  for (int tc = 0; tc < 16; ++tc) {
    // issue next-tile stage (async; drained by the next __syncthreads)
    if (tc < 15) {
#pragma unroll
      for (int i = 0; i < 4; ++i) {
        int p = i * 512 + tid;
        int br = p >> 5, kc = p & 31;
        gload_lds16(
            xbf + (size_t)(colbase + (tc + 1) * 64 + br) * 256 + ((kc ^ (br & 7)) * 8),
            smem + (buf ^ 1) * 32768 + p * 16);
      }
    }
    float sqj[4];
#pragma unroll
    for (int n = 0; n < 4; ++n) sqj[n] = sq[colbase + tc * 64 + n * 16 + c];

    f32x4 acc[2][4];
#pragma unroll
    for (int m = 0; m < 2; ++m)
#pragma unroll
      for (int n = 0; n < 4; ++n) acc[m][n] = (f32x4){0.f, 0.f, 0.f, 0.f};

    const char* Bb = smem + buf * 32768;
#pragma unroll
    for (int kb = 0; kb < 8; ++kb) {
      bf16x8 b[4];
#pragma unroll
      for (int n = 0; n < 4; ++n)
        b[n] = *reinterpret_cast<const bf16x8*>(
            Bb + (n * 16 + c) * 512 + (((kb * 4 + g) ^ l7) * 16));
#pragma unroll
      for (int m = 0; m < 2; ++m) {
        bf16x8 av = __builtin_bit_cast(bf16x8, afr[m * 8 + kb]);
#pragma unroll
        for (int n = 0; n < 4; ++n)
          acc[m][n] = __builtin_amdgcn_mfma_f32_16x16x32_bf16(av, b[n], acc[m][n], 0, 0, 0);
      }
    }
    // scores -> LDS (col-major, stride 260 dwords)
#pragma unroll
    for (int m = 0; m < 2; ++m)
#pragma unroll
      for (int n = 0; n < 4; ++n) {
        f32x4 v;
#pragma unroll
        for (int e = 0; e < 4; ++e)
          v[e] = sqi[m * 4 + e] + sqj[n] - 2.0f * acc[m][n][e];
        int col  = n * 16 + c;
        int row0 = w * 32 + m * 16 + g * 4;
        *reinterpret_cast<f32x4*>(scores + col * 260 + row0) = v;
      }
    __syncthreads();
    // scan: thread owns (row srow, 32-col half-slice)
#pragma unroll 8
    for (int u = 0; u < 32; ++u) {
      int col = shalf * 32 + u;
      float f = scores[col * 260 + srow];
      int gcol = colbase + tc * 64 + col;
      insert6(f, gcol, lv, lcx);
    }
    __syncthreads();
    buf ^= 1;
  }
  // pack candidates: key = (quantized score << 13) | col
#pragma unroll
  for (int j = 0; j < 6; ++j) {
    uint32_t q = (uint32_t)fminf(fmaxf(lv[j] * 512.0f, 0.0f), 524287.0f);
    cand[(size_t)(rowbase + srow) * 96 + chunk * 12 + shalf * 6 + j] =
        (q << 13) | (uint32_t)(lcx[j] & 8191);
  }
}

// ------------------------ kernel 3: rescore + emit -------------------------
// One wave per row: select 16 smallest keys of 96, fp32-rescore each with the
// EXACT round-4 summation order, top-6 lex, PRNG pick, fused output write.
__global__ __launch_bounds__(256)
void rescore_emit_kernel(const float* __restrict__ x,
                         const float* __restrict__ sq,
                         const uint32_t* __restrict__ cand,
                         float* __restrict__ out) {
  const int tid = threadIdx.x;
  const int wid = tid >> 6;
  const int l   = tid & 63;
  const int row = blockIdx.x * 4 + wid;

  uint32_t k0 = cand[(size_t)row * 96 + l];
  uint32_t k1 = (l < 32) ? cand[(size_t)row * 96 + 64 + l] : 0xFFFFFFFFu;
  int mycol = row;
#pragma unroll
  for (int it = 0; it < 16; ++it) {
    uint32_t v = k0 < k1 ? k0 : k1;
#pragma unroll
    for (int off = 1; off < 64; off <<= 1) {
      uint32_t o = __shfl_xor(v, off);
      v = o < v ? o : v;
    }
    if (l == it) mycol = (int)(v & 8191u);
    if (k0 == v) k0 = 0xFFFFFFFFu;
    else if (k1 == v) k1 = 0xFFFFFFFFu;
  }

  // fp32 rescore (lanes 0..15 hold the 16 candidates) — round-4 exact order
  const float4* x4 = reinterpret_cast<const float4*>(x);
  float acc = 0.0f;
#pragma unroll 4
  for (int d4 = 0; d4 < 64; ++d4) {
    float4 a = x4[(size_t)row * 64 + d4];
    float4 b = x4[(size_t)mycol * 64 + d4];
    acc = fmaf(a.x, b.x, acc);
    acc = fmaf(a.y, b.y, acc);
    acc = fmaf(a.z, b.z, acc);
    acc = fmaf(a.w, b.w, acc);
  }
  float s2 = sq[row] + sq[mycol];
  float myscore = s2 - 2.0f * acc;

  float v6[6]; int i6[6];
#pragma unroll
  for (int j = 0; j < 6; ++j) { v6[j] = 3.402823466e38f; i6[j] = 0x7fffffff; }
#pragma unroll
  for (int j = 0; j < 16; ++j) {
    float scj = __shfl(myscore, j);
    int   ccj = __shfl(mycol, j);
    insert6(scj, ccj, v6, i6);
  }

  // PRNG (partitionable threefry; verbatim from the round-4 PASS)
  uint32_t rg0 = 0, rg1 = 0; tf2x32(0u, 42u, rg0, rg1);
  uint32_t kc0 = 0, kc1 = 0; tf2x32(rg0, rg1, kc0, kc1);
  uint32_t ka0 = 0, ka1 = 1; tf2x32(rg0, rg1, ka0, ka1);
  uint32_t k10 = 0, k11 = 0; tf2x32(kc0, kc1, k10, k11);
  uint32_t k20 = 0, k21 = 1; tf2x32(kc0, kc1, k20, k21);

  uint32_t ri = (uint32_t)row;
  uint32_t h0 = 0, h1 = ri; tf2x32(k10, k11, h0, h1); uint32_t hb = h0 ^ h1;
  uint32_t l0 = 0, l1 = ri; tf2x32(k20, k21, l0, l1); uint32_t lb = l0 ^ l1;
  uint32_t u0 = 0, u1 = ri; tf2x32(ka0, ka1, u0, u1); uint32_t ub = u0 ^ u1;

  uint32_t ch = (hb % 5u + lb % 5u) % 5u;
  float al = __uint_as_float((ub >> 9) | 0x3F800000u) - 1.0f;
  al = fmaxf(0.0f, al);

  int sl = i6[1];
  sl = (ch == 1u) ? i6[2] : sl;
  sl = (ch == 2u) ? i6[3] : sl;
  sl = (ch == 3u) ? i6[4] : sl;
  sl = (ch == 4u) ? i6[5] : sl;

  // emit: copy row + augmented row (mul/mul/add, no FMA contraction)
  float4 xi = x4[(size_t)row * 64 + l];
  float4 xs = x4[(size_t)sl * 64 + l];
  float om = 1.0f - al;
  float4 o;
  o.x = __fadd_rn(__fmul_rn(om, xi.x), __fmul_rn(al, xs.x));
  o.y = __fadd_rn(__fmul_rn(om, xi.y), __fmul_rn(al, xs.y));
  o.z = __fadd_rn(__fmul_rn(om, xi.z), __fmul_rn(al, xs.z));
  o.w = __fadd_rn(__fmul_rn(om, xi.w), __fmul_rn(al, xs.w));
  float4* out4 = reinterpret_cast<float4*>(out);
  out4[(size_t)row * 64 + l] = xi;
  out4[(size_t)(NROWS + row) * 64 + l] = o;
}

// ------------------------------- launcher ----------------------------------
extern "C" void kernel_launch(void* const* d_in, const int* in_sizes, int n_in,
                              void* d_out, int out_size, void* d_ws, size_t ws_size,
                              hipStream_t stream) {
  const float* x = (const float*)d_in[0];
  float* out = (float*)d_out;
  char* ws = (char*)d_ws;

  // ws layout: sq (32KB) | xbf (4MB) | cand (3MB)  ~= 7.03MB
  float* sq = (float*)ws;
  unsigned short* xbf = (unsigned short*)(ws + 32768);
  uint32_t* cand = (uint32_t*)(ws + 32768 + 4194304);

  hipLaunchKernelGGL(prep_kernel,         dim3(2048), dim3(256), 0, stream, x, sq, xbf);
  hipLaunchKernelGGL(gemm_topk_kernel,    dim3(256),  dim3(512), 0, stream, xbf, sq, cand);
  hipLaunchKernelGGL(rescore_emit_kernel, dim3(2048), dim3(256), 0, stream, x, sq, cand, out);
}

// Round 7
// 120.948 us; speedup vs baseline: 7.3093x; 2.3100x over previous
//
#include <hip/hip_runtime.h>
#include <stdint.h>

// ---------------------------------------------------------------------------
// ManifoldAugmentation: x (8192,256) fp32 ->
//   out = concat([x, (1-alpha)*x + alpha*x[sel]]) (16384,256) fp32
// Stage 1: bf16 MFMA GEMM; per-tile scores quantized (19-bit, round-5-proven)
//          and packed (q<<13)|col into LDS; branchless top-6 -> 192 cand/row
// Stage 2: fp32 rescore of top-16 candidates, bit-exact round-4 score order
// PRNG: JAX threefry, partitionable semantics (verified PASS rounds 4-5).
// ---------------------------------------------------------------------------

#define NROWS 8192
#define ND4   64

typedef __attribute__((ext_vector_type(8))) short bf16x8;
typedef __attribute__((ext_vector_type(4))) float f32x4;

__device__ __forceinline__ uint32_t umin32(uint32_t a, uint32_t b) { return a < b ? a : b; }
__device__ __forceinline__ uint32_t umax32(uint32_t a, uint32_t b) { return a > b ? a : b; }

// ------------------------- threefry2x32 (20 rounds) ------------------------
__device__ __forceinline__ uint32_t rotl32(uint32_t v, int d) {
  return (v << d) | (v >> (32 - d));
}

__device__ __forceinline__ void tf2x32(uint32_t k0, uint32_t k1,
                                       uint32_t& x0, uint32_t& x1) {
  const uint32_t ks2 = k0 ^ k1 ^ 0x1BD11BDAu;
  x0 += k0; x1 += k1;
#define TFR(R) { x0 += x1; x1 = rotl32(x1, R); x1 ^= x0; }
  TFR(13) TFR(15) TFR(26) TFR(6)
  x0 += k1;  x1 += ks2 + 1u;
  TFR(17) TFR(29) TFR(16) TFR(24)
  x0 += ks2; x1 += k0 + 2u;
  TFR(13) TFR(15) TFR(26) TFR(6)
  x0 += k0;  x1 += k1 + 3u;
  TFR(17) TFR(29) TFR(16) TFR(24)
  x0 += k1;  x1 += ks2 + 4u;
  TFR(13) TFR(15) TFR(26) TFR(6)
  x0 += ks2; x1 += k0 + 5u;
#undef TFR
}

// --------------------- top-6 (val,idx) lexicographic (fp32 stage) ----------
__device__ __forceinline__ bool lessp(float a, int ai, float b, int bi) {
  return (a < b) || ((a == b) && (ai < bi));
}

__device__ __forceinline__ void insert6(float key, int idx,
                                        float (&v)[6], int (&ix)[6]) {
  if (!lessp(key, idx, v[5], ix[5])) return;
#pragma unroll
  for (int j = 5; j >= 1; --j) {
    if (lessp(key, idx, v[j - 1], ix[j - 1])) {
      v[j] = v[j - 1]; ix[j] = ix[j - 1];
    } else {
      v[j] = key; ix[j] = idx; return;
    }
  }
  v[0] = key; ix[0] = idx;
}

// ----------------------------- small helpers -------------------------------
__device__ __forceinline__ unsigned short f2bf(float f) {
  uint32_t u = __float_as_uint(f);
  u += 0x7FFFu + ((u >> 16) & 1u);          // RNE
  return (unsigned short)(u >> 16);
}

__device__ __forceinline__ void gload_lds16(const void* g, void* l) {
  __builtin_amdgcn_global_load_lds(
      (const __attribute__((address_space(1))) unsigned int*)g,
      (__attribute__((address_space(3))) unsigned int*)l, 16, 0, 0);
}

// ------------------------------ kernel 1: prep -----------------------------
__global__ void prep_kernel(const float* __restrict__ x,
                            float* __restrict__ sq,
                            unsigned short* __restrict__ xbf) {
  int row  = blockIdx.x * 4 + (threadIdx.x >> 6);
  int lane = threadIdx.x & 63;
  const float4* xv4 = reinterpret_cast<const float4*>(x);
  float4 vv = xv4[(size_t)row * ND4 + lane];
  float t = vv.x * vv.x + vv.y * vv.y + vv.z * vv.z + vv.w * vv.w;
#pragma unroll
  for (int off = 32; off >= 1; off >>= 1) t += __shfl_down(t, off);
  if (lane == 0) sq[row] = t;
  ushort4 st;
  st.x = f2bf(vv.x); st.y = f2bf(vv.y); st.z = f2bf(vv.z); st.w = f2bf(vv.w);
  *reinterpret_cast<ushort4*>(xbf + (size_t)row * 256 + lane * 4) = st;
}

// --------------------------- kernel 2: gemm+topk ---------------------------
// grid 512 = 32 row-blocks (256 rows) x 16 col-chunks (512 cols); 512 thr.
// 8 waves x 32-row stripes; A-frags in regs; B-tile (32x256 bf16, 16KB)
// double-buffered via global_load_lds; epilogue quantizes scores to 19-bit
// (key=(q<<13)|col, round-5-proven) into LDS (odd stride 269, conflict-free);
// scan = branchless u32 sorted-6 bubble.
__global__ __launch_bounds__(512, 4)
void gemm_topk_kernel(const unsigned short* __restrict__ xbf,
                      const float* __restrict__ sq,
                      uint32_t* __restrict__ cand) {
  __shared__ __align__(16) char smem[67200];   // 2x16KB B + 34432B keys
  uint32_t* skeys = reinterpret_cast<uint32_t*>(smem + 32768);

  const int tid = threadIdx.x;
  const int bid = blockIdx.x;
  const int rowblk = bid & 31;
  const int chunk  = bid >> 5;
  const int rowbase = rowblk * 256;
  const int colbase = chunk * 512;
  const int w = tid >> 6;
  const int l = tid & 63;
  const int g = l >> 4;
  const int c = l & 15;

  // A fragments: rows rowbase + w*32 + m*16 + c, k-unit (4kb+g)
  uint4 afr[16];
#pragma unroll
  for (int m = 0; m < 2; ++m)
#pragma unroll
    for (int kb = 0; kb < 8; ++kb)
      afr[m * 8 + kb] = *reinterpret_cast<const uint4*>(
          xbf + (size_t)(rowbase + w * 32 + m * 16 + c) * 256 + (4 * kb + g) * 8);

  float sqi[8];
#pragma unroll
  for (int m = 0; m < 2; ++m)
#pragma unroll
    for (int e = 0; e < 4; ++e)
      sqi[m * 4 + e] = sq[rowbase + w * 32 + m * 16 + g * 4 + e];

  uint32_t v[6];
#pragma unroll
  for (int j = 0; j < 6; ++j) v[j] = 0xFFFFFFFFu;
  const int srow = tid >> 1, shalf = tid & 1;

  // prologue: stage tile 0 into buf 0 (2 issue rounds x 512 x 16B = 16KB)
#pragma unroll
  for (int i = 0; i < 2; ++i) {
    int p = i * 512 + tid;
    int br = p >> 5, kc = p & 31;
    gload_lds16(xbf + (size_t)(colbase + br) * 256 + ((kc ^ (br & 7)) * 8),
                smem + p * 16);
  }
  __syncthreads();

  int buf = 0;
  for (int tc = 0; tc < 16; ++tc) {
    if (tc < 15) {
#pragma unroll
      for (int i = 0; i < 2; ++i) {
        int p = i * 512 + tid;
        int br = p >> 5, kc = p & 31;
        gload_lds16(
            xbf + (size_t)(colbase + (tc + 1) * 32 + br) * 256 + ((kc ^ (br & 7)) * 8),
            smem + (buf ^ 1) * 16384 + p * 16);
      }
    }
    float sqj[2];
#pragma unroll
    for (int n = 0; n < 2; ++n) sqj[n] = sq[colbase + tc * 32 + n * 16 + c];

    f32x4 acc[2][2];
#pragma unroll
    for (int m = 0; m < 2; ++m)
#pragma unroll
      for (int n = 0; n < 2; ++n) acc[m][n] = (f32x4){0.f, 0.f, 0.f, 0.f};

    const char* Bb = smem + buf * 16384;
#pragma unroll
    for (int kb = 0; kb < 8; ++kb) {
      bf16x8 b[2];
#pragma unroll
      for (int n = 0; n < 2; ++n)
        b[n] = *reinterpret_cast<const bf16x8*>(
            Bb + (n * 16 + c) * 512 + (((kb * 4 + g) ^ ((n * 16 + c) & 7)) * 16));
#pragma unroll
      for (int m = 0; m < 2; ++m) {
        bf16x8 av = __builtin_bit_cast(bf16x8, afr[m * 8 + kb]);
#pragma unroll
        for (int n = 0; n < 2; ++n)
          acc[m][n] = __builtin_amdgcn_mfma_f32_16x16x32_bf16(av, b[n], acc[m][n], 0, 0, 0);
      }
    }
    // epilogue: quantize to 19 bits (round-5-proven: q=min(s*512,524287)),
    // pack (q<<13)|col -> LDS (col-major, odd stride 269)
#pragma unroll
    for (int m = 0; m < 2; ++m)
#pragma unroll
      for (int n = 0; n < 2; ++n)
#pragma unroll
        for (int e = 0; e < 4; ++e) {
          float s = sqi[m * 4 + e] + sqj[n] - 2.0f * acc[m][n][e];
          s = fmaxf(s, 0.0f);
          uint32_t q = (uint32_t)fminf(s * 512.0f, 524287.0f);
          uint32_t key = (q << 13) |
                         (uint32_t)(colbase + tc * 32 + n * 16 + c);
          int rl = w * 32 + m * 16 + g * 4 + e;
          skeys[(n * 16 + c) * 269 + rl] = key;
        }
    __syncthreads();
    // scan: thread owns (row srow, 16-col half of the 32-col tile)
#pragma unroll
    for (int u = 0; u < 16; ++u) {
      uint32_t t = skeys[(shalf * 16 + u) * 269 + srow];
#pragma unroll
      for (int j = 0; j < 6; ++j) {
        uint32_t vj = v[j];
        v[j] = umin32(vj, t);
        t    = umax32(vj, t);
      }
    }
    __syncthreads();
    buf ^= 1;
  }
#pragma unroll
  for (int j = 0; j < 6; ++j)
    cand[(size_t)(rowbase + srow) * 192 + chunk * 12 + shalf * 6 + j] = v[j];
}

// ------------------------ kernel 3: rescore + emit -------------------------
// One wave per row: select 16 smallest of 192 packed keys, fp32-rescore each
// with the EXACT round-4 summation order, top-6 lex, PRNG pick, fused write.
__global__ __launch_bounds__(256)
void rescore_emit_kernel(const float* __restrict__ x,
                         const float* __restrict__ sq,
                         const uint32_t* __restrict__ cand,
                         float* __restrict__ out) {
  const int tid = threadIdx.x;
  const int wid = tid >> 6;
  const int l   = tid & 63;
  const int row = blockIdx.x * 4 + wid;

  uint32_t k0 = cand[(size_t)row * 192 + l];
  uint32_t k1 = cand[(size_t)row * 192 + 64 + l];
  uint32_t k2 = cand[(size_t)row * 192 + 128 + l];
  int mycol = row;
#pragma unroll
  for (int it = 0; it < 16; ++it) {
    uint32_t mv = umin32(k0, umin32(k1, k2));
#pragma unroll
    for (int off = 1; off < 64; off <<= 1) {
      uint32_t o = __shfl_xor(mv, off);
      mv = umin32(mv, o);
    }
    if (l == it) mycol = (int)(mv & 8191u);
    if (k0 == mv) k0 = 0xFFFFFFFFu;
    else if (k1 == mv) k1 = 0xFFFFFFFFu;
    else if (k2 == mv) k2 = 0xFFFFFFFFu;
  }

  // fp32 rescore (lanes 0..15 hold the 16 candidates) — round-4 exact order
  const float4* x4 = reinterpret_cast<const float4*>(x);
  float acc = 0.0f;
#pragma unroll 4
  for (int d4 = 0; d4 < 64; ++d4) {
    float4 a = x4[(size_t)row * 64 + d4];
    float4 b = x4[(size_t)mycol * 64 + d4];
    acc = fmaf(a.x, b.x, acc);
    acc = fmaf(a.y, b.y, acc);
    acc = fmaf(a.z, b.z, acc);
    acc = fmaf(a.w, b.w, acc);
  }
  float s2 = sq[row] + sq[mycol];
  float myscore = s2 - 2.0f * acc;

  float v6[6]; int i6[6];
#pragma unroll
  for (int j = 0; j < 6; ++j) { v6[j] = 3.402823466e38f; i6[j] = 0x7fffffff; }
#pragma unroll
  for (int j = 0; j < 16; ++j) {
    float scj = __shfl(myscore, j);
    int   ccj = __shfl(mycol, j);
    insert6(scj, ccj, v6, i6);
  }

  // PRNG (partitionable threefry; verbatim from rounds 4-5 PASS)
  uint32_t rg0 = 0, rg1 = 0; tf2x32(0u, 42u, rg0, rg1);
  uint32_t kc0 = 0, kc1 = 0; tf2x32(rg0, rg1, kc0, kc1);
  uint32_t ka0 = 0, ka1 = 1; tf2x32(rg0, rg1, ka0, ka1);
  uint32_t k10 = 0, k11 = 0; tf2x32(kc0, kc1, k10, k11);
  uint32_t k20 = 0, k21 = 1; tf2x32(kc0, kc1, k20, k21);

  uint32_t ri = (uint32_t)row;
  uint32_t h0 = 0, h1 = ri; tf2x32(k10, k11, h0, h1); uint32_t hb = h0 ^ h1;
  uint32_t l0 = 0, l1 = ri; tf2x32(k20, k21, l0, l1); uint32_t lb = l0 ^ l1;
  uint32_t u0 = 0, u1 = ri; tf2x32(ka0, ka1, u0, u1); uint32_t ub = u0 ^ u1;

  uint32_t ch = (hb % 5u + lb % 5u) % 5u;
  float al = __uint_as_float((ub >> 9) | 0x3F800000u) - 1.0f;
  al = fmaxf(0.0f, al);

  int sl = i6[1];
  sl = (ch == 1u) ? i6[2] : sl;
  sl = (ch == 2u) ? i6[3] : sl;
  sl = (ch == 3u) ? i6[4] : sl;
  sl = (ch == 4u) ? i6[5] : sl;

  // emit: copy row + augmented row (mul/mul/add, no FMA contraction)
  float4 xi = x4[(size_t)row * 64 + l];
  float4 xs = x4[(size_t)sl * 64 + l];
  float om = 1.0f - al;
  float4 o;
  o.x = __fadd_rn(__fmul_rn(om, xi.x), __fmul_rn(al, xs.x));
  o.y = __fadd_rn(__fmul_rn(om, xi.y), __fmul_rn(al, xs.y));
  o.z = __fadd_rn(__fmul_rn(om, xi.z), __fmul_rn(al, xs.z));
  o.w = __fadd_rn(__fmul_rn(om, xi.w), __fmul_rn(al, xs.w));
  float4* out4 = reinterpret_cast<float4*>(out);
  out4[(size_t)row * 64 + l] = xi;
  out4[(size_t)(NROWS + row) * 64 + l] = o;
}

// ------------------------------- launcher ----------------------------------
extern "C" void kernel_launch(void* const* d_in, const int* in_sizes, int n_in,
                              void* d_out, int out_size, void* d_ws, size_t ws_size,
                              hipStream_t stream) {
  const float* x = (const float*)d_in[0];
  float* out = (float*)d_out;
  char* ws = (char*)d_ws;

  // ws layout: sq (32KB) | xbf (4MB) | cand (6.29MB)  ~= 10.5MB
  float* sq = (float*)ws;
  unsigned short* xbf = (unsigned short*)(ws + 32768);
  uint32_t* cand = (uint32_t*)(ws + 32768 + 4194304);

  hipLaunchKernelGGL(prep_kernel,         dim3(2048), dim3(256), 0, stream, x, sq, xbf);
  hipLaunchKernelGGL(gemm_topk_kernel,    dim3(512),  dim3(512), 0, stream, xbf, sq, cand);
  hipLaunchKernelGGL(rescore_emit_kernel, dim3(2048), dim3(256), 0, stream, x, sq, cand, out);
}